// Round 2
// baseline (82.318 us; speedup 1.0000x reference)
//
#include <hip/hip_runtime.h>

constexpr int N  = 128;
constexpr int C  = 2048;
constexpr int KP = 4;
constexpr int KN = 508;
constexpr int K  = 512;   // KP + KN

// One wave (64 lanes) computes one logit: dot(inputs[n], M[idx]) over C=2048.
// 4 waves per 256-thread block; blockIdx.y = n so inputs row is cache-hot.
__global__ __launch_bounds__(256) void logits_kernel(
    const float* __restrict__ inputs,
    const int*   __restrict__ pos_idx,
    const int*   __restrict__ neg_idx,
    const float* __restrict__ M,
    float*       __restrict__ logits)
{
    const int wave = threadIdx.x >> 6;
    const int lane = threadIdx.x & 63;
    const int n    = blockIdx.y;
    const int k    = (blockIdx.x << 2) + wave;

    const int idx = (k < KP) ? pos_idx[n * KP + k]
                             : neg_idx[n * KN + (k - KP)];

    const float4* __restrict__ a = reinterpret_cast<const float4*>(inputs + (size_t)n * C);
    const float4* __restrict__ b = reinterpret_cast<const float4*>(M + (size_t)idx * C);

    float acc = 0.f;
    #pragma unroll
    for (int i = 0; i < C / (4 * 64); ++i) {   // 8 iterations, 16 B/lane each
        float4 av = a[i * 64 + lane];
        float4 bv = b[i * 64 + lane];
        acc = fmaf(av.x, bv.x, acc);
        acc = fmaf(av.y, bv.y, acc);
        acc = fmaf(av.z, bv.z, acc);
        acc = fmaf(av.w, bv.w, acc);
    }

    #pragma unroll
    for (int off = 32; off > 0; off >>= 1)
        acc += __shfl_down(acc, off, 64);

    if (lane == 0) logits[n * K + k] = acc;
}

// One block per row n: log-softmax denominator over K=512, then the
// weighted positive-logit partial loss for this row (deterministic).
__global__ __launch_bounds__(512) void softmax_loss_kernel(
    const float* __restrict__ logits,
    const float* __restrict__ cof,
    float*       __restrict__ row_loss)
{
    __shared__ float red[8];
    __shared__ float xs[KP];
    const int n    = blockIdx.x;
    const int t    = threadIdx.x;
    const int wid  = t >> 6;
    const int lane = t & 63;

    float x = logits[n * K + t];

    // block max
    float m = x;
    #pragma unroll
    for (int off = 1; off < 64; off <<= 1)
        m = fmaxf(m, __shfl_xor(m, off, 64));
    if (lane == 0) red[wid] = m;
    __syncthreads();
    float bm = red[0];
    #pragma unroll
    for (int i = 1; i < 8; ++i) bm = fmaxf(bm, red[i]);

    // block sum of exp
    float s = expf(x - bm);
    #pragma unroll
    for (int off = 1; off < 64; off <<= 1)
        s += __shfl_xor(s, off, 64);
    __syncthreads();
    if (lane == 0) red[wid] = s;
    if (t < KP) xs[t] = x;
    __syncthreads();

    if (t == 0) {
        float bs = 0.f;
        #pragma unroll
        for (int i = 0; i < 8; ++i) bs += red[i];
        const float logZ = bm + logf(bs);
        float acc = 0.f;
        #pragma unroll
        for (int j = 0; j < KP; ++j)
            acc += cof[j] * (xs[j] - logZ);
        row_loss[n] = acc;   // = sum_j cof[j] * logp[n, j]
    }
}

// Single block: deterministic fixed-order reduction of 128 row losses.
__global__ __launch_bounds__(128) void loss_reduce_kernel(
    const float* __restrict__ row_loss,
    float*       __restrict__ out)
{
    const int t = threadIdx.x;
    float v = row_loss[t];
    #pragma unroll
    for (int off = 1; off < 64; off <<= 1)
        v += __shfl_xor(v, off, 64);
    __shared__ float red[2];
    if ((t & 63) == 0) red[t >> 6] = v;
    __syncthreads();
    if (t == 0) out[0] = -(red[0] + red[1]) / (float)N;
}

extern "C" void kernel_launch(void* const* d_in, const int* in_sizes, int n_in,
                              void* d_out, int out_size, void* d_ws, size_t ws_size,
                              hipStream_t stream) {
    const float* inputs  = (const float*)d_in[0];
    const int*   pos_idx = (const int*)d_in[1];
    const int*   neg_idx = (const int*)d_in[2];
    const float* cof     = (const float*)d_in[3];
    const float* M       = (const float*)d_in[4];

    float* out      = (float*)d_out;
    float* logits   = out + 1;          // d_out = [loss(1), logits(128*512)]
    float* row_loss = (float*)d_ws;     // 128 floats of scratch

    logits_kernel<<<dim3(K / 4, N), 256, 0, stream>>>(inputs, pos_idx, neg_idx, M, logits);
    softmax_loss_kernel<<<N, K, 0, stream>>>(logits, cof, row_loss);
    loss_reduce_kernel<<<1, N, 0, stream>>>(row_loss, out);
}